// Round 12
// baseline (691.083 us; speedup 1.0000x reference)
//
#include <hip/hip_runtime.h>
#include <hip/hip_fp8.h>
#include <math.h>

typedef __attribute__((ext_vector_type(8))) _Float16 f16x8;
typedef __attribute__((ext_vector_type(4))) _Float16 f16x4;
typedef __attribute__((ext_vector_type(4))) float f32x4;

// ---------------------------------------------------------------------------
// Precision: every activation a = hi(fp16) + lo/2048, lo quantized fp8-e4m3.
// |lo| <= fp16-ulp-scale => combined rel err <= 2^-15 — the band r11 proved
// invisible (absmax bit-identical across 2^-23 -> 2^-15 on msc).
// GEMM products: hi@Wh + (hi@Wl + lo@Wh)/2048, W planes fp16 (tiny).
//
// Round 12: lo-planes of h, x, p1 -> fp8 (msc already fp16+fp8 from r11).
// Saves ~175 MB of fabric traffic across 15 h-touches + x/p1. XOR swizzle
// removed everywhere (vestigial since r10 dropped LDS).
// Layouts per (rowblock rb, slab s):
//   hi page: 32 rows x 32 fp16 (64 B/row), octet c at r*32 + c*8 (elems)
//   lo page: 32 rows x 32 fp8  (32 B/row), octet c at r*32 + c*8 (bytes)
// Frag loads are 16-row x 64 B (hi) / x 32 B (lo) contiguous — coalesced.
// ---------------------------------------------------------------------------

__device__ __forceinline__ float fp8_to_f32(unsigned char b) {
    __hip_fp8_e4m3 v;
    v.__x = b;
    return static_cast<float>(v);
}
__device__ __forceinline__ unsigned char f32_to_fp8(float x) {
    return __hip_fp8_e4m3(x).__x;
}
__device__ __forceinline__ f16x8 dec_lo8(const unsigned char* p) {
    uint2 u = *reinterpret_cast<const uint2*>(p);
    const unsigned char* b = (const unsigned char*)&u;
    f16x8 o;
#pragma unroll
    for (int j = 0; j < 8; ++j) o[j] = (_Float16)fp8_to_f32(b[j]);
    return o;
}

// ------------------------- graph setup -------------------------------------
__global__ void scan1_kernel(const int* __restrict__ cnt, int M,
                             int* __restrict__ rowptr, int* __restrict__ bsum,
                             float* __restrict__ dinv) {
    __shared__ int s[256];
    int t = threadIdx.x;
    int i = blockIdx.x * 256 + t;
    int v = (i < M) ? cnt[i] : 0;
    s[t] = v; __syncthreads();
    for (int o = 1; o < 256; o <<= 1) {
        int x = (t >= o) ? s[t - o] : 0;
        __syncthreads();
        s[t] += x;
        __syncthreads();
    }
    if (i < M) {
        rowptr[i] = s[t] - v;
        dinv[i] = rsqrtf((float)v + 1.0f);  // deg = in-deg + self-loop
    }
    if (t == 255) bsum[blockIdx.x] = s[255];
}

__global__ void scan2_kernel(const int* __restrict__ bsum, int nb, int* __restrict__ boff) {
    __shared__ int s[256];
    int t = threadIdx.x;
    int v = (t < nb) ? bsum[t] : 0;
    s[t] = v; __syncthreads();
    for (int o = 1; o < 256; o <<= 1) {
        int x = (t >= o) ? s[t - o] : 0;
        __syncthreads();
        s[t] += x;
        __syncthreads();
    }
    if (t < nb) boff[t] = s[t] - v;
}

__global__ void scan3_kernel(int* __restrict__ rowptr, int M, int E, const int* __restrict__ boff) {
    int i = blockIdx.x * 256 + threadIdx.x;
    if (i < M) rowptr[i] += boff[blockIdx.x];
    if (i == M) rowptr[M] = E;
}

__global__ void fill_kernel(const int* __restrict__ src, const int* __restrict__ dst, int E,
                            const int* __restrict__ rowptr, int* __restrict__ cursor,
                            int* __restrict__ csr) {
    int i = blockIdx.x * blockDim.x + threadIdx.x;
    if (i < E) {
        int d = dst[i];
        int slot = atomicAdd(&cursor[d], 1);
        csr[rowptr[d] + slot] = src[i];
    }
}

// ---------------- fused prep: count + convert_x + pack_b --------------------
struct WSeg { const float* src; _Float16* dh; _Float16* dl; int K; int N; };
struct WSegs { WSeg s[8]; };

__global__ void prep_kernel(const int* __restrict__ dst, int E, int* __restrict__ cnt,
                            const float* __restrict__ x,
                            _Float16* __restrict__ xHi, unsigned char* __restrict__ xLo,
                            int M, int xchunks, WSegs segs,
                            int nCount, int nConv) {
    int b = blockIdx.x;
    if (b < nCount) {
        int i = b * 256 + threadIdx.x;
        if (i < E) atomicAdd(&cnt[dst[i]], 1);
        return;
    }
    b -= nCount;
    if (b < nConv) {
        // x -> hi/lo pages (4 slabs); one 8-feature octet per thread
        int g = b * 256 + threadIdx.x;
        if (g >= xchunks) return;
        int c = g & 3;
        int r = (g >> 2) & 31;
        int s = (g >> 7) & 3;
        int rb = g >> 9;
        int node = rb * 32 + r;
        int k = s * 32 + c * 8;
        f16x8 hv = {};
        unsigned long long lv = 0ull;
        if (node < M) {
            const float* xr = x + (size_t)node * 128 + k;
            unsigned char* lb = (unsigned char*)&lv;
#pragma unroll
            for (int j = 0; j < 8; ++j) {
                float v = xr[j];
                _Float16 hi = (_Float16)v;
                hv[j] = hi;
                lb[j] = f32_to_fp8((v - (float)hi) * 2048.f);
            }
        }
        size_t pbase = ((size_t)(rb * 4 + s) * 32 + r) * 32 + c * 8;
        *reinterpret_cast<f16x8*>(xHi + pbase) = hv;
        *reinterpret_cast<unsigned long long*>(xLo + pbase) = lv;
        return;
    }
    b -= nConv;
    // pack_b: frag-major WT planes (fp16 both), flat i = ((s*G+g)*64+l)*8+j
    WSeg sg = segs.s[b / 144];
    int i = (b % 144) * 256 + threadIdx.x;
    if (i >= sg.K * sg.N) return;
    int G = sg.N >> 4;
    int s = i / (G * 512);
    int r = i - s * (G * 512);
    int g = r >> 9;
    int r2 = r & 511;
    int l = r2 >> 3, j = r2 & 7;
    int n = g * 16 + (l & 15);
    int k = s * 32 + (l >> 4) * 8 + j;
    float w = sg.src[(size_t)k * sg.N + n];
    _Float16 hi = (_Float16)w;
    sg.dh[i] = hi;
    sg.dl[i] = (_Float16)((w - (float)hi) * 2048.f);
}

// ---------------------------------------------------------------------------
// Barrier-free LDS-free split MFMA GEMM (r10 structure; A-lo now fp8).
// 256 thr = 4 waves, 32 rows/block, wave w -> cols [w*48,+48) (NN=192).
// OM bit0: msc out (fp16 hi row-major + fp8 lo row-major).
// OM bit1: hi/lo packed pages out. rowscale applied before quantize.
// ---------------------------------------------------------------------------
template <int KK, int NN, int ACT, int OM>
__global__ __launch_bounds__(256, 4) void mfma_gemm(
    const _Float16* __restrict__ AHi, const unsigned char* __restrict__ ALo,
    const _Float16* __restrict__ Bph, const _Float16* __restrict__ Bpl,
    const float* __restrict__ bias, const float* __restrict__ rowscale,
    _Float16* __restrict__ Ch16, unsigned char* __restrict__ C8,
    _Float16* __restrict__ CpHi, unsigned char* __restrict__ CpLo, int M) {
    constexpr int NS = KK / 32;
    constexpr int G = NN / 16;
    constexpr int MT = 2;
    constexpr int NSO = NN / 32;

    const int tid = threadIdx.x;
    const int wave = tid >> 6, lane = tid & 63;
    const int quad = lane >> 4, l16 = lane & 15;
    const int n0 = wave * 48;
    const int g0 = n0 >> 4;
    const int row0 = blockIdx.x * 32;

    f32x4 acc[MT][3], acc2[MT][3];
#pragma unroll
    for (int mt = 0; mt < MT; ++mt)
#pragma unroll
        for (int nt = 0; nt < 3; ++nt) {
            acc[mt][nt] = (f32x4){0.f, 0.f, 0.f, 0.f};
            acc2[mt][nt] = (f32x4){0.f, 0.f, 0.f, 0.f};
        }

#pragma unroll
    for (int s = 0; s < NS; ++s) {
        const _Float16* pgHi = AHi + (size_t)(blockIdx.x * NS + s) * 1024;
        const unsigned char* pgLo = ALo + (size_t)(blockIdx.x * NS + s) * 1024;
        f16x8 ah[MT], al[MT];
#pragma unroll
        for (int mt = 0; mt < MT; ++mt) {
            int R = mt * 16 + l16;
            ah[mt] = *reinterpret_cast<const f16x8*>(pgHi + R * 32 + quad * 8);
            al[mt] = dec_lo8(pgLo + R * 32 + quad * 8);
        }
        f16x8 bh[3], bl[3];
#pragma unroll
        for (int nt = 0; nt < 3; ++nt) {
            size_t o = ((size_t)(s * G + g0 + nt) * 64 + lane) * 8;
            bh[nt] = *reinterpret_cast<const f16x8*>(Bph + o);
            bl[nt] = *reinterpret_cast<const f16x8*>(Bpl + o);
        }
#pragma unroll
        for (int mt = 0; mt < MT; ++mt)
#pragma unroll
            for (int nt = 0; nt < 3; ++nt) {
                acc[mt][nt] = __builtin_amdgcn_mfma_f32_16x16x32_f16(ah[mt], bh[nt], acc[mt][nt], 0, 0, 0);
                acc2[mt][nt] = __builtin_amdgcn_mfma_f32_16x16x32_f16(ah[mt], bl[nt], acc2[mt][nt], 0, 0, 0);
                acc2[mt][nt] = __builtin_amdgcn_mfma_f32_16x16x32_f16(al[mt], bh[nt], acc2[mt][nt], 0, 0, 0);
            }
    }

    // epilogue: C/D layout col=lane&15, row=quad*4+reg
    float bv[3];
#pragma unroll
    for (int nt = 0; nt < 3; ++nt) bv[nt] = bias ? bias[n0 + nt * 16 + l16] : 0.f;
#pragma unroll
    for (int mt = 0; mt < MT; ++mt)
#pragma unroll
        for (int i = 0; i < 4; ++i) {
            int row = row0 + mt * 16 + quad * 4 + i;
            if (row < M) {
                float rs = rowscale ? rowscale[row] : 1.f;
#pragma unroll
                for (int nt = 0; nt < 3; ++nt) {
                    int col = n0 + nt * 16 + l16;
                    float v = acc[mt][nt][i] + acc2[mt][nt][i] * (1.f / 2048.f) + bv[nt];
                    if (ACT == 1) v = fmaxf(v, 0.f);
                    v *= rs;
                    _Float16 hi = (_Float16)v;
                    if (OM & 1) {
                        Ch16[(size_t)row * NN + col] = hi;
                        C8[(size_t)row * NN + col] = f32_to_fp8((v - (float)hi) * 2048.f);
                    }
                    if (OM & 2) {
                        int os = col >> 5, w32 = col & 31;
                        size_t pbase = ((size_t)((row >> 5) * NSO + os) * 32 + (row & 31)) * 32 + w32;
                        CpHi[pbase] = hi;
                        CpLo[pbase] = f32_to_fp8((v - (float)hi) * 2048.f);
                    }
                }
            }
        }
}

// ---------------------------------------------------------------------------
// fp16+fp8 whole-row aggregation (r11 gather, at its 8xXCD-fill floor).
// h update now fp16-hi + fp8-lo pages.
// ---------------------------------------------------------------------------
__global__ __launch_bounds__(256) void aggregate_kernel(
    const _Float16* __restrict__ msch, const unsigned char* __restrict__ mscl,
    const int* __restrict__ csr, const int* __restrict__ rowptr,
    const float* __restrict__ dinv, const float* __restrict__ bias,
    _Float16* __restrict__ hHi, unsigned char* __restrict__ hLo, int M) {
    int wid = (blockIdx.x * 256 + threadIdx.x) >> 6;
    int lane = threadIdx.x & 63;
    if (wid >= M || lane >= 48) return;

    f16x4 sh = *reinterpret_cast<const f16x4*>(msch + (size_t)wid * 192 + lane * 4);
    uchar4 sl = *reinterpret_cast<const uchar4*>(mscl + (size_t)wid * 192 + lane * 4);
    float4 ah0 = make_float4((float)sh[0], (float)sh[1], (float)sh[2], (float)sh[3]);
    float4 al0 = make_float4(fp8_to_f32(sl.x), fp8_to_f32(sl.y),
                             fp8_to_f32(sl.z), fp8_to_f32(sl.w));
    float4 ah1 = make_float4(0.f, 0.f, 0.f, 0.f);
    float4 al1 = make_float4(0.f, 0.f, 0.f, 0.f);

    int beg = rowptr[wid], end = rowptr[wid + 1];
    int e = beg;
    for (; e + 1 < end; e += 2) {
        int s0 = csr[e], s1 = csr[e + 1];
        f16x4 h0 = *reinterpret_cast<const f16x4*>(msch + (size_t)s0 * 192 + lane * 4);
        uchar4 l0 = *reinterpret_cast<const uchar4*>(mscl + (size_t)s0 * 192 + lane * 4);
        f16x4 h1 = *reinterpret_cast<const f16x4*>(msch + (size_t)s1 * 192 + lane * 4);
        uchar4 l1 = *reinterpret_cast<const uchar4*>(mscl + (size_t)s1 * 192 + lane * 4);
        ah0.x += (float)h0[0]; ah0.y += (float)h0[1]; ah0.z += (float)h0[2]; ah0.w += (float)h0[3];
        al0.x += fp8_to_f32(l0.x); al0.y += fp8_to_f32(l0.y);
        al0.z += fp8_to_f32(l0.z); al0.w += fp8_to_f32(l0.w);
        ah1.x += (float)h1[0]; ah1.y += (float)h1[1]; ah1.z += (float)h1[2]; ah1.w += (float)h1[3];
        al1.x += fp8_to_f32(l1.x); al1.y += fp8_to_f32(l1.y);
        al1.z += fp8_to_f32(l1.z); al1.w += fp8_to_f32(l1.w);
    }
    if (e < end) {
        int s0 = csr[e];
        f16x4 h0 = *reinterpret_cast<const f16x4*>(msch + (size_t)s0 * 192 + lane * 4);
        uchar4 l0 = *reinterpret_cast<const uchar4*>(mscl + (size_t)s0 * 192 + lane * 4);
        ah0.x += (float)h0[0]; ah0.y += (float)h0[1]; ah0.z += (float)h0[2]; ah0.w += (float)h0[3];
        al0.x += fp8_to_f32(l0.x); al0.y += fp8_to_f32(l0.y);
        al0.z += fp8_to_f32(l0.z); al0.w += fp8_to_f32(l0.w);
    }
    float4 a;
    a.x = (ah0.x + ah1.x) + (al0.x + al1.x) * (1.f / 2048.f);
    a.y = (ah0.y + ah1.y) + (al0.y + al1.y) * (1.f / 2048.f);
    a.z = (ah0.z + ah1.z) + (al0.z + al1.z) * (1.f / 2048.f);
    a.w = (ah0.w + ah1.w) + (al0.w + al1.w) * (1.f / 2048.f);

    float dn = dinv[wid];
    float4 b = reinterpret_cast<const float4*>(bias)[lane];

    // packed-h granule for features f0 = lane*4 .. +4
    int f0 = lane * 4;
    int s = f0 >> 5, w32 = f0 & 31;
    size_t pbase = ((size_t)((wid >> 5) * 6 + s) * 32 + (wid & 31)) * 32 + w32;
    f16x4* hp = reinterpret_cast<f16x4*>(hHi + pbase);
    uchar4* lp = reinterpret_cast<uchar4*>(hLo + pbase);
    f16x4 hh = *hp;
    uchar4 hl = *lp;
    float4 hv;
    hv.x = (float)hh[0] + fp8_to_f32(hl.x) * (1.f / 2048.f) + fmaxf(a.x * dn + b.x, 0.f);
    hv.y = (float)hh[1] + fp8_to_f32(hl.y) * (1.f / 2048.f) + fmaxf(a.y * dn + b.y, 0.f);
    hv.z = (float)hh[2] + fp8_to_f32(hl.z) * (1.f / 2048.f) + fmaxf(a.z * dn + b.z, 0.f);
    hv.w = (float)hh[3] + fp8_to_f32(hl.w) * (1.f / 2048.f) + fmaxf(a.w * dn + b.w, 0.f);
    f16x4 nh = {(_Float16)hv.x, (_Float16)hv.y, (_Float16)hv.z, (_Float16)hv.w};
    uchar4 nl;
    nl.x = f32_to_fp8((hv.x - (float)nh[0]) * 2048.f);
    nl.y = f32_to_fp8((hv.y - (float)nh[1]) * 2048.f);
    nl.z = f32_to_fp8((hv.z - (float)nh[2]) * 2048.f);
    nl.w = f32_to_fp8((hv.w - (float)nh[3]) * 2048.f);
    *hp = nh;
    *lp = nl;
}

// ---------------------------------------------------------------------------
// Fused tail: p2 = relu(p1@Wp2+b), r = relu(h@Wr1+b) direct-load MFMA;
// then pos = p2·Wp3+bp3, rad = sigmoid(r·Wr2+br2),
// out = pos/(|pos|+1e-8)*rad. 32 rows/block.
// ---------------------------------------------------------------------------
__global__ __launch_bounds__(256, 2) void tail_kernel(
    const _Float16* __restrict__ p1Hi, const unsigned char* __restrict__ p1Lo,
    const _Float16* __restrict__ hHi, const unsigned char* __restrict__ hLo,
    const _Float16* __restrict__ W2h, const _Float16* __restrict__ W2l,
    const _Float16* __restrict__ Wrh, const _Float16* __restrict__ Wrl,
    const float* __restrict__ bp2, const float* __restrict__ br1,
    const float* __restrict__ Wp3, const float* __restrict__ bp3,
    const float* __restrict__ Wr2, const float* __restrict__ br2,
    float* __restrict__ out, int M) {
    __shared__ float p2t[32 * 96];
    __shared__ float rbt[32 * 96];
    const int tid = threadIdx.x;
    const int wave = tid >> 6, lane = tid & 63;
    const int quad = lane >> 4, l16 = lane & 15;
    const int m0 = (wave >> 1) * 16;
    const int n0 = (wave & 1) * 48;
    const int g0 = n0 >> 4;  // G = 6
    const int row0 = blockIdx.x * 32;

    f32x4 aP[3], aP2[3], aR[3], aR2[3];
#pragma unroll
    for (int nt = 0; nt < 3; ++nt) {
        aP[nt] = (f32x4){0.f, 0.f, 0.f, 0.f};
        aP2[nt] = aP[nt]; aR[nt] = aP[nt]; aR2[nt] = aP[nt];
    }

#pragma unroll
    for (int s = 0; s < 6; ++s) {
        const _Float16* pgPHi = p1Hi + (size_t)(blockIdx.x * 6 + s) * 1024;
        const unsigned char* pgPLo = p1Lo + (size_t)(blockIdx.x * 6 + s) * 1024;
        const _Float16* pgHHi = hHi + (size_t)(blockIdx.x * 6 + s) * 1024;
        const unsigned char* pgHLo = hLo + (size_t)(blockIdx.x * 6 + s) * 1024;
        int R = m0 + l16;
        f16x8 p1h = *reinterpret_cast<const f16x8*>(pgPHi + R * 32 + quad * 8);
        f16x8 p1l = dec_lo8(pgPLo + R * 32 + quad * 8);
        f16x8 hh = *reinterpret_cast<const f16x8*>(pgHHi + R * 32 + quad * 8);
        f16x8 hl = dec_lo8(pgHLo + R * 32 + quad * 8);
        f16x8 b2h[3], b2l[3], brh[3], brl[3];
#pragma unroll
        for (int nt = 0; nt < 3; ++nt) {
            size_t o = ((size_t)(s * 6 + g0 + nt) * 64 + lane) * 8;
            b2h[nt] = *reinterpret_cast<const f16x8*>(W2h + o);
            b2l[nt] = *reinterpret_cast<const f16x8*>(W2l + o);
            brh[nt] = *reinterpret_cast<const f16x8*>(Wrh + o);
            brl[nt] = *reinterpret_cast<const f16x8*>(Wrl + o);
        }
#pragma unroll
        for (int nt = 0; nt < 3; ++nt) {
            aP[nt] = __builtin_amdgcn_mfma_f32_16x16x32_f16(p1h, b2h[nt], aP[nt], 0, 0, 0);
            aP2[nt] = __builtin_amdgcn_mfma_f32_16x16x32_f16(p1h, b2l[nt], aP2[nt], 0, 0, 0);
            aP2[nt] = __builtin_amdgcn_mfma_f32_16x16x32_f16(p1l, b2h[nt], aP2[nt], 0, 0, 0);
            aR[nt] = __builtin_amdgcn_mfma_f32_16x16x32_f16(hh, brh[nt], aR[nt], 0, 0, 0);
            aR2[nt] = __builtin_amdgcn_mfma_f32_16x16x32_f16(hh, brl[nt], aR2[nt], 0, 0, 0);
            aR2[nt] = __builtin_amdgcn_mfma_f32_16x16x32_f16(hl, brh[nt], aR2[nt], 0, 0, 0);
        }
    }

#pragma unroll
    for (int i = 0; i < 4; ++i) {
        int row = m0 + quad * 4 + i;  // 0..31
#pragma unroll
        for (int nt = 0; nt < 3; ++nt) {
            int col = n0 + nt * 16 + l16;
            float v2 = aP[nt][i] + aP2[nt][i] * (1.f / 2048.f) + bp2[col];
            float vr = aR[nt][i] + aR2[nt][i] * (1.f / 2048.f) + br1[col];
            p2t[row * 96 + col] = fmaxf(v2, 0.f);
            rbt[row * 96 + col] = fmaxf(vr, 0.f);
        }
    }
    __syncthreads();

    if (tid < 32) {
        int row = row0 + tid;
        if (row < M) {
            float a0 = 0.f, a1 = 0.f, rr = 0.f;
            const float* p = p2t + tid * 96;
            const float* r = rbt + tid * 96;
#pragma unroll
            for (int j = 0; j < 96; ++j) {
                a0 += p[j] * Wp3[j * 2 + 0];
                a1 += p[j] * Wp3[j * 2 + 1];
                rr += r[j] * Wr2[j];
            }
            a0 += bp3[0];
            a1 += bp3[1];
            rr += br2[0];
            float radius = 1.f / (1.f + expf(-rr));
            float nrm = sqrtf(a0 * a0 + a1 * a1) + 1e-8f;
            float sc = radius / nrm;
            out[(size_t)row * 2 + 0] = a0 * sc;
            out[(size_t)row * 2 + 1] = a1 * sc;
        }
    }
}

extern "C" void kernel_launch(void* const* d_in, const int* in_sizes, int n_in,
                              void* d_out, int out_size, void* d_ws, size_t ws_size,
                              hipStream_t stream) {
    const float* x     = (const float*)d_in[0];
    const int*   ei    = (const int*)d_in[1];
    const float* Wp    = (const float*)d_in[2];
    const float* bp    = (const float*)d_in[3];
    const float* convW = (const float*)d_in[4];
    const float* convB = (const float*)d_in[5];
    const float* Wp1   = (const float*)d_in[6];
    const float* bp1   = (const float*)d_in[7];
    const float* Wp2   = (const float*)d_in[8];
    const float* bp2   = (const float*)d_in[9];
    const float* Wp3   = (const float*)d_in[10];
    const float* bp3   = (const float*)d_in[11];
    const float* Wr1   = (const float*)d_in[12];
    const float* br1   = (const float*)d_in[13];
    const float* Wr2   = (const float*)d_in[14];
    const float* br2   = (const float*)d_in[15];
    float* out = (float*)d_out;

    const int M = in_sizes[0] / 128;  // 50000
    const int E = in_sizes[1] / 2;    // 800000
    const int* srcI = ei;
    const int* dstI = ei + E;
    const int RBp = (M + 31) / 32;    // 1563 32-row pages / GEMM blocks
    const int Mr  = RBp * 32;

    char* w = (char*)d_ws;
    size_t off = 0;
    auto alloc = [&](size_t b) { size_t o = off; off += (b + 255) & ~(size_t)255; return o; };
    // msc region (28.8 MB) also hosts p1 hi+lo later (19.2 + 9.6)
    char*          mscreg = w + alloc((size_t)RBp * 6 * 4096);
    _Float16*      hHi  = (_Float16*)(w + alloc((size_t)RBp * 6 * 2048));
    unsigned char* hLo  = (unsigned char*)(w + alloc((size_t)RBp * 6 * 1024));
    _Float16*      xHi  = (_Float16*)(w + alloc((size_t)RBp * 4 * 2048));
    unsigned char* xLo  = (unsigned char*)(w + alloc((size_t)RBp * 4 * 1024));
    _Float16* WpPh  = (_Float16*)(w + alloc((size_t)128 * 192 * 2));
    _Float16* WpPl  = (_Float16*)(w + alloc((size_t)128 * 192 * 2));
    _Float16* cWPh  = (_Float16*)(w + alloc((size_t)4 * 192 * 192 * 2));
    _Float16* cWPl  = (_Float16*)(w + alloc((size_t)4 * 192 * 192 * 2));
    _Float16* Wp1Ph = (_Float16*)(w + alloc((size_t)192 * 192 * 2));
    _Float16* Wp1Pl = (_Float16*)(w + alloc((size_t)192 * 192 * 2));
    _Float16* Wp2Ph = (_Float16*)(w + alloc((size_t)192 * 96 * 2));
    _Float16* Wp2Pl = (_Float16*)(w + alloc((size_t)192 * 96 * 2));
    _Float16* Wr1Ph = (_Float16*)(w + alloc((size_t)192 * 96 * 2));
    _Float16* Wr1Pl = (_Float16*)(w + alloc((size_t)192 * 96 * 2));
    int*      cnt    = (int*)(w + alloc((size_t)M * 4));
    int*      cursor = (int*)(w + alloc((size_t)M * 4));
    float*    dinv   = (float*)(w + alloc((size_t)M * 4));
    int*      rowptr = (int*)(w + alloc((size_t)(M + 1) * 4));
    int*      csr    = (int*)(w + alloc((size_t)(E + 64) * 4));
    int*      bsum   = (int*)(w + alloc(256 * 4));
    int*      boff   = (int*)(w + alloc(256 * 4));

    _Float16*      msch = (_Float16*)mscreg;                                  // 19.2 MB
    unsigned char* mscl = (unsigned char*)(mscreg + (size_t)Mr * 192 * 2);    // 9.6 MB
    _Float16*      p1Hi = (_Float16*)mscreg;                                  // alias after last aggregate
    unsigned char* p1Lo = (unsigned char*)(mscreg + (size_t)RBp * 6 * 2048);

    hipMemsetAsync(cnt, 0, (size_t)((char*)cursor - (char*)cnt) + (size_t)M * 4, stream);

    // fused prep: count + convert_x + pack_b
    const int xchunks = RBp * 512;
    const int nCount = (E + 255) / 256;
    const int nConv  = (xchunks + 255) / 256;
    WSegs segs;
    segs.s[0] = {Wp, WpPh, WpPl, 128, 192};
    segs.s[1] = {convW + 0 * 192 * 192, cWPh + 0 * 192 * 192, cWPl + 0 * 192 * 192, 192, 192};
    segs.s[2] = {convW + 1 * 192 * 192, cWPh + 1 * 192 * 192, cWPl + 1 * 192 * 192, 192, 192};
    segs.s[3] = {convW + 2 * 192 * 192, cWPh + 2 * 192 * 192, cWPl + 2 * 192 * 192, 192, 192};
    segs.s[4] = {convW + 3 * 192 * 192, cWPh + 3 * 192 * 192, cWPl + 3 * 192 * 192, 192, 192};
    segs.s[5] = {Wp1, Wp1Ph, Wp1Pl, 192, 192};
    segs.s[6] = {Wp2, Wp2Ph, Wp2Pl, 192, 96};
    segs.s[7] = {Wr1, Wr1Ph, Wr1Pl, 192, 96};
    prep_kernel<<<nCount + nConv + 8 * 144, 256, 0, stream>>>(
        dstI, E, cnt, x, xHi, xLo, M, xchunks, segs, nCount, nConv);

    int nb = (M + 255) / 256;
    scan1_kernel<<<nb, 256, 0, stream>>>(cnt, M, rowptr, bsum, dinv);
    scan2_kernel<<<1, 256, 0, stream>>>(bsum, nb, boff);
    scan3_kernel<<<(M + 256) / 256, 256, 0, stream>>>(rowptr, M, E, boff);
    fill_kernel<<<(E + 255) / 256, 256, 0, stream>>>(srcI, dstI, E, rowptr, cursor, csr);

    // h = x @ Wp + bp -> hi/lo pages
    mfma_gemm<128, 192, 0, 2><<<RBp, 256, 0, stream>>>(
        xHi, xLo, WpPh, WpPl, bp, nullptr, nullptr, nullptr, hHi, hLo, M);
    // 4 GCN layers: msc = (h@W)*dinv -> fp16+fp8 row-major; whole-row aggregate
    for (int i = 0; i < 4; i++) {
        mfma_gemm<192, 192, 0, 1><<<RBp, 256, 0, stream>>>(
            hHi, hLo, cWPh + (size_t)i * 192 * 192, cWPl + (size_t)i * 192 * 192,
            nullptr, dinv, msch, mscl, nullptr, nullptr, M);
        aggregate_kernel<<<(M + 3) / 4, 256, 0, stream>>>(
            msch, mscl, csr, rowptr, dinv, convB + (size_t)i * 192, hHi, hLo, M);
    }
    // p1 = relu(h @ Wp1 + bp1) -> hi/lo pages (alias msc region)
    mfma_gemm<192, 192, 1, 2><<<RBp, 256, 0, stream>>>(
        hHi, hLo, Wp1Ph, Wp1Pl, bp1, nullptr, nullptr, nullptr, p1Hi, p1Lo, M);
    // fused p2/r GEMMs + finalize
    tail_kernel<<<RBp, 256, 0, stream>>>(
        p1Hi, p1Lo, hHi, hLo, Wp2Ph, Wp2Pl, Wr1Ph, Wr1Pl, bp2, br1,
        Wp3, bp3, Wr2, br2, out, M);
}